// Round 13
// baseline (131.176 us; speedup 1.0000x reference)
//
#include <hip/hip_runtime.h>

// Sizes fixed by the reference problem.
#define B_   4
#define NQ_  128
#define NK_  1024
#define DD_  256   // DQ == DK
#define H_   256
#define DV_  256

__device__ __forceinline__ float wave_sum(float v) {
  #pragma unroll
  for (int o = 32; o; o >>= 1) v += __shfl_xor(v, o);
  return v;
}
__device__ __forceinline__ float wave_max(float v) {
  #pragma unroll
  for (int o = 32; o; o >>= 1) v = fmaxf(v, __shfl_xor(v, o));
  return v;
}

// Merged projection GEMM over 4608 rows (32-row x 64-col tiles, 576 blocks, BK=32):
//   rows [0,512):    qp[row][h]   = queries * W_q   (row-major store)
//   rows [512,4608): kpT[b][h][k] = keys * W_k      (transposed store via LDS)
// 256 threads, 2x4 micro-tile, 1-tile register prefetch, 8 k-iterations.
__global__ __launch_bounds__(256) void proj_merged_kernel(
    const float* __restrict__ queries, const float* __restrict__ keys,
    const float* __restrict__ W_q, const float* __restrict__ W_k,
    float* __restrict__ qp, float* __restrict__ kpT) {
  __shared__ float As[32 * 36];   // [k32][row32] (+pad)
  __shared__ float Ws[32 * 68];   // [k32][col64] (+pad)
  __shared__ float Ts[64 * 36];   // transpose staging [h64][k32] (+pad)
  const int tid  = threadIdx.x;
  const int row0 = blockIdx.x * 32;
  const int col0 = blockIdx.y * 64;
  const bool isQ = row0 < 512;
  const float* A = isQ ? queries + (size_t)row0 * DD_
                       : keys + (size_t)(row0 - 512) * DD_;
  const float* W = isQ ? W_q : W_k;
  const int ld_d = tid & 31, ld_r = tid >> 5;   // A loader: 32 k x 8 r (x4 passes)
  const int lw_n = tid & 63, lw_k = tid >> 6;   // W loader: 64 n x 4 k (x8 passes)
  const int tn = tid & 15, tm = tid >> 4;       // compute: 16 cols x 16 rows

  float aP[4], wP[8];
  #pragma unroll
  for (int p = 0; p < 4; ++p) aP[p] = A[(size_t)(p * 8 + ld_r) * DD_ + ld_d];
  #pragma unroll
  for (int p = 0; p < 8; ++p) wP[p] = W[(size_t)(p * 4 + lw_k) * H_ + col0 + lw_n];

  float acc[2][4] = {};
  for (int kt = 0; kt < 8; ++kt) {
    __syncthreads();   // previous compute done reading LDS
    #pragma unroll
    for (int p = 0; p < 4; ++p) As[ld_d * 36 + p * 8 + ld_r] = aP[p];
    #pragma unroll
    for (int p = 0; p < 8; ++p) Ws[(p * 4 + lw_k) * 68 + lw_n] = wP[p];
    __syncthreads();
    if (kt < 7) {      // prefetch next k-tile while computing this one
      const int k0 = (kt + 1) * 32;
      #pragma unroll
      for (int p = 0; p < 4; ++p) aP[p] = A[(size_t)(p * 8 + ld_r) * DD_ + k0 + ld_d];
      #pragma unroll
      for (int p = 0; p < 8; ++p) wP[p] = W[(size_t)(k0 + p * 4 + lw_k) * H_ + col0 + lw_n];
    }
    #pragma unroll
    for (int kk = 0; kk < 32; ++kk) {
      const float2 a = *(const float2*)&As[kk * 36 + tm * 2];
      const float4 w = *(const float4*)&Ws[kk * 68 + tn * 4];
      acc[0][0] = fmaf(a.x, w.x, acc[0][0]);
      acc[0][1] = fmaf(a.x, w.y, acc[0][1]);
      acc[0][2] = fmaf(a.x, w.z, acc[0][2]);
      acc[0][3] = fmaf(a.x, w.w, acc[0][3]);
      acc[1][0] = fmaf(a.y, w.x, acc[1][0]);
      acc[1][1] = fmaf(a.y, w.y, acc[1][1]);
      acc[1][2] = fmaf(a.y, w.z, acc[1][2]);
      acc[1][3] = fmaf(a.y, w.w, acc[1][3]);
    }
  }

  if (isQ) {
    #pragma unroll
    for (int i = 0; i < 2; ++i) {
      *(float4*)&qp[(size_t)(row0 + tm * 2 + i) * H_ + col0 + tn * 4] =
          make_float4(acc[i][0], acc[i][1], acc[i][2], acc[i][3]);
    }
  } else {
    // Transpose 32(k) x 64(h) tile in LDS, then coalesced float4 stores.
    #pragma unroll
    for (int i = 0; i < 2; ++i)
      #pragma unroll
      for (int j = 0; j < 4; ++j)
        Ts[(tn * 4 + j) * 36 + tm * 2 + i] = acc[i][j];
    __syncthreads();
    const int keyrow = row0 - 512;
    const int b = keyrow >> 10;            // NK_=1024 rows per batch
    const int kbase = keyrow & (NK_ - 1);
    const int hh = tid >> 2;               // 64 h rows
    const int kg = (tid & 3) * 8;          // 8-k group within the 32-k tile
    float* dst = kpT + ((size_t)(b * H_ + col0 + hh)) * NK_ + kbase + kg;
    #pragma unroll
    for (int p = 0; p < 2; ++p)
      *(float4*)&dst[p * 4] = *(const float4*)&Ts[hh * 36 + kg + p * 4];
  }
}

// Fused scores + masked softmax + PV.  One block per q row; 256 threads (4 waves);
// grid 512 -> 2 blocks/CU so phases of different blocks overlap.
// Phase 1: thread t owns k = 4t..4t+3, full h loop (256) with 4-deep float4
//   register prefetch. score = wsum - sum_h (2 v_h)*rcp(1+exp2((q_h+k_h)*2*log2e)).
//   Threads with k >= valid_len skip the loop; scores stay in registers.
// Phase 2: in-register masked softmax (wave shuffles + LDS cross-wave reduce);
//   only final weights are written to LDS.
// Phase 3: wave w owns k in [256w, 256w+256) ∩ [0,vl); lane owns d = 4*lane,
//   4-deep V prefetch; partials combined through LDS.
__global__ __launch_bounds__(256) void fused_attn_kernel(
    const float* __restrict__ qp, const float* __restrict__ kpT,
    const float* __restrict__ v_w, const float* __restrict__ values,
    const int* __restrict__ valid_lens, float* __restrict__ out) {
  __shared__ float qs[H_];          // q * C2
  __shared__ float w2s[H_];         // 2 * v_w
  __shared__ float reds[4];
  __shared__ float wlds[NK_];       // final softmax weights
  __shared__ float redm[4];
  __shared__ float redsum[4];
  __shared__ float red[4][DV_];

  const int tid = threadIdx.x;  // 0..255
  // Batch<->XCD affinity: XCD pair {2b,2b+1} only touches batch b.
  const int n = blockIdx.x;     // 0..511
  const int xcd = n & 7;
  const int b = xcd >> 1;
  const int idx = ((n >> 3) << 1) | (xcd & 1);  // 0..127 q row within batch
  const int qrow = b * NQ_ + idx;

  int vl = valid_lens[b];
  vl = vl < 1 ? 1 : (vl > NK_ ? NK_ : vl);

  const float C2 = 2.8853900817779268f;  // 2*log2(e)
  {
    const float vw = v_w[tid];
    w2s[tid] = 2.0f * vw;
    qs[tid] = qp[(size_t)qrow * H_ + tid] * C2;
    float s = wave_sum(vw);
    if ((tid & 63) == 0) reds[tid >> 6] = s;
  }
  __syncthreads();
  const float wsum = reds[0] + reds[1] + reds[2] + reds[3];

  // ---- Phase 1: scores (kept in registers) ----
  const int k0 = tid * 4;
  float ax = 0.f, ay = 0.f, az = 0.f, aw = 0.f;
  if (k0 < vl) {
    const float* kp = kpT + ((size_t)(b * H_)) * NK_ + k0;
    float4 c0 = *(const float4*)(kp + 0 * (size_t)NK_);
    float4 c1 = *(const float4*)(kp + 1 * (size_t)NK_);
    float4 c2 = *(const float4*)(kp + 2 * (size_t)NK_);
    float4 c3 = *(const float4*)(kp + 3 * (size_t)NK_);
#define CONSUME(kv, h)                                                     \
    {                                                                      \
      const float w2 = w2s[h];                                             \
      const float qc = qs[h];                                              \
      const float ex = __builtin_amdgcn_exp2f(fmaf((kv).x, C2, qc));       \
      const float ey = __builtin_amdgcn_exp2f(fmaf((kv).y, C2, qc));       \
      const float ez = __builtin_amdgcn_exp2f(fmaf((kv).z, C2, qc));       \
      const float ew = __builtin_amdgcn_exp2f(fmaf((kv).w, C2, qc));       \
      ax = fmaf(w2, __builtin_amdgcn_rcpf(1.0f + ex), ax);                 \
      ay = fmaf(w2, __builtin_amdgcn_rcpf(1.0f + ey), ay);                 \
      az = fmaf(w2, __builtin_amdgcn_rcpf(1.0f + ez), az);                 \
      aw = fmaf(w2, __builtin_amdgcn_rcpf(1.0f + ew), aw);                 \
    }
    for (int gg = 0; gg < 63; ++gg) {
      const int hb = gg * 4;
      const float4 n0 = *(const float4*)(kp + (size_t)(hb + 4) * NK_);
      const float4 n1 = *(const float4*)(kp + (size_t)(hb + 5) * NK_);
      const float4 n2 = *(const float4*)(kp + (size_t)(hb + 6) * NK_);
      const float4 n3 = *(const float4*)(kp + (size_t)(hb + 7) * NK_);
      CONSUME(c0, hb + 0)
      CONSUME(c1, hb + 1)
      CONSUME(c2, hb + 2)
      CONSUME(c3, hb + 3)
      c0 = n0; c1 = n1; c2 = n2; c3 = n3;
    }
    CONSUME(c0, 252)
    CONSUME(c1, 253)
    CONSUME(c2, 254)
    CONSUME(c3, 255)
#undef CONSUME
  }
  const float s0 = wsum - ax;
  const float s1 = wsum - ay;
  const float s2 = wsum - az;
  const float s3 = wsum - aw;

  // ---- Phase 2: masked softmax, in-register ----
  const float NEG = -3.0e38f;
  float m = NEG;
  m = fmaxf(m, (k0 + 0 < vl) ? s0 : NEG);
  m = fmaxf(m, (k0 + 1 < vl) ? s1 : NEG);
  m = fmaxf(m, (k0 + 2 < vl) ? s2 : NEG);
  m = fmaxf(m, (k0 + 3 < vl) ? s3 : NEG);
  m = wave_max(m);
  if ((tid & 63) == 0) redm[tid >> 6] = m;
  __syncthreads();
  const float M = fmaxf(fmaxf(redm[0], redm[1]), fmaxf(redm[2], redm[3]));
  const float CE = 1.4426950408889634f;  // log2(e)
  const float p0 = (k0 + 0 < vl) ? __builtin_amdgcn_exp2f((s0 - M) * CE) : 0.0f;
  const float p1 = (k0 + 1 < vl) ? __builtin_amdgcn_exp2f((s1 - M) * CE) : 0.0f;
  const float p2 = (k0 + 2 < vl) ? __builtin_amdgcn_exp2f((s2 - M) * CE) : 0.0f;
  const float p3 = (k0 + 3 < vl) ? __builtin_amdgcn_exp2f((s3 - M) * CE) : 0.0f;
  float psum = wave_sum(p0 + p1 + p2 + p3);
  if ((tid & 63) == 0) redsum[tid >> 6] = psum;
  __syncthreads();
  const float S = redsum[0] + redsum[1] + redsum[2] + redsum[3];
  const float inv = 1.0f / S;
  *(float4*)&wlds[k0] = make_float4(p0 * inv, p1 * inv, p2 * inv, p3 * inv);
  __syncthreads();

  // ---- Phase 3: PV with 4-deep V prefetch ----
  const int w = tid >> 6;
  const int lane = tid & 63;
  const int d0 = lane * 4;
  float4 pa = make_float4(0.f, 0.f, 0.f, 0.f);
  const int kbeg = w * (NK_ / 4);
  const int kend = (kbeg + NK_ / 4) < vl ? (kbeg + NK_ / 4) : vl;
  const float* vb = values + (size_t)b * NK_ * DV_ + d0;
#define PVSTEP(v4, kk)                                                     \
    {                                                                      \
      const float w0 = wlds[kk];                                           \
      pa.x = fmaf(w0, (v4).x, pa.x);                                       \
      pa.y = fmaf(w0, (v4).y, pa.y);                                       \
      pa.z = fmaf(w0, (v4).z, pa.z);                                       \
      pa.w = fmaf(w0, (v4).w, pa.w);                                       \
    }
  int k = kbeg;
  if (k + 4 <= kend) {
    float4 v0 = *(const float4*)(vb + (size_t)(k + 0) * DV_);
    float4 v1 = *(const float4*)(vb + (size_t)(k + 1) * DV_);
    float4 v2 = *(const float4*)(vb + (size_t)(k + 2) * DV_);
    float4 v3 = *(const float4*)(vb + (size_t)(k + 3) * DV_);
    for (; k + 8 <= kend; k += 4) {
      const float4 u0 = *(const float4*)(vb + (size_t)(k + 4) * DV_);
      const float4 u1 = *(const float4*)(vb + (size_t)(k + 5) * DV_);
      const float4 u2 = *(const float4*)(vb + (size_t)(k + 6) * DV_);
      const float4 u3 = *(const float4*)(vb + (size_t)(k + 7) * DV_);
      PVSTEP(v0, k + 0)
      PVSTEP(v1, k + 1)
      PVSTEP(v2, k + 2)
      PVSTEP(v3, k + 3)
      v0 = u0; v1 = u1; v2 = u2; v3 = u3;
    }
    PVSTEP(v0, k + 0)
    PVSTEP(v1, k + 1)
    PVSTEP(v2, k + 2)
    PVSTEP(v3, k + 3)
    k += 4;
  }
  for (; k < kend; ++k) {
    const float4 v4 = *(const float4*)(vb + (size_t)k * DV_);
    PVSTEP(v4, k)
  }
#undef PVSTEP
  *(float4*)&red[w][d0] = pa;
  __syncthreads();

  // Combine 4 wave-partials; coalesced store.
  const float s = red[0][tid] + red[1][tid] + red[2][tid] + red[3][tid];
  out[(size_t)qrow * DV_ + tid] = s;
}

extern "C" void kernel_launch(void* const* d_in, const int* in_sizes, int n_in,
                              void* d_out, int out_size, void* d_ws, size_t ws_size,
                              hipStream_t stream) {
  const float* queries = (const float*)d_in[0];  // (B, NQ, DQ)
  const float* keys    = (const float*)d_in[1];  // (B, NK, DK)
  const float* values  = (const float*)d_in[2];  // (B, NK, DV)
  const int*   vlens   = (const int*)d_in[3];    // (B,)
  const float* W_q     = (const float*)d_in[4];  // (DQ, H)
  const float* W_k     = (const float*)d_in[5];  // (DK, H)
  const float* v_w     = (const float*)d_in[6];  // (H,)
  float* out = (float*)d_out;                    // (B, NQ, DV)

  // Workspace layout (floats): qp | kpT  = 0.5MB + 4MB
  float* qp  = (float*)d_ws;                  // [B*NQ][H]
  float* kpT = qp + (size_t)B_ * NQ_ * H_;    // [B][H][NK]

  proj_merged_kernel<<<dim3((512 + B_ * NK_) / 32, H_ / 64), 256, 0, stream>>>(
      queries, keys, W_q, W_k, qp, kpT);
  fused_attn_kernel<<<B_ * NQ_, 256, 0, stream>>>(qp, kpT, v_w, values, vlens, out);
}

// Round 15
// 121.884 us; speedup vs baseline: 1.0762x; 1.0762x over previous
//
#include <hip/hip_runtime.h>

// Sizes fixed by the reference problem.
#define B_   4
#define NQ_  128
#define NK_  1024
#define DD_  256   // DQ == DK
#define H_   256
#define DV_  256

__device__ __forceinline__ float wave_sum(float v) {
  #pragma unroll
  for (int o = 32; o; o >>= 1) v += __shfl_xor(v, o);
  return v;
}
__device__ __forceinline__ float wave_max(float v) {
  #pragma unroll
  for (int o = 32; o; o >>= 1) v = fmaxf(v, __shfl_xor(v, o));
  return v;
}

// Merged projection GEMM over 4608 rows (32-row x 64-col tiles, 576 blocks, BK=32):
//   rows [0,512):    qp[row][h]   = queries * W_q   (row-major store)
//   rows [512,4608): kpT[b][h][k] = keys * W_k      (transposed store via LDS)
__global__ __launch_bounds__(256) void proj_merged_kernel(
    const float* __restrict__ queries, const float* __restrict__ keys,
    const float* __restrict__ W_q, const float* __restrict__ W_k,
    float* __restrict__ qp, float* __restrict__ kpT) {
  __shared__ float As[32 * 36];   // [k32][row32] (+pad)
  __shared__ float Ws[32 * 68];   // [k32][col64] (+pad)
  __shared__ float Ts[64 * 36];   // transpose staging [h64][k32] (+pad)
  const int tid  = threadIdx.x;
  const int row0 = blockIdx.x * 32;
  const int col0 = blockIdx.y * 64;
  const bool isQ = row0 < 512;
  const float* A = isQ ? queries + (size_t)row0 * DD_
                       : keys + (size_t)(row0 - 512) * DD_;
  const float* W = isQ ? W_q : W_k;
  const int ld_d = tid & 31, ld_r = tid >> 5;   // A loader: 32 k x 8 r (x4 passes)
  const int lw_n = tid & 63, lw_k = tid >> 6;   // W loader: 64 n x 4 k (x8 passes)
  const int tn = tid & 15, tm = tid >> 4;       // compute: 16 cols x 16 rows

  float aP[4], wP[8];
  #pragma unroll
  for (int p = 0; p < 4; ++p) aP[p] = A[(size_t)(p * 8 + ld_r) * DD_ + ld_d];
  #pragma unroll
  for (int p = 0; p < 8; ++p) wP[p] = W[(size_t)(p * 4 + lw_k) * H_ + col0 + lw_n];

  float acc[2][4] = {};
  for (int kt = 0; kt < 8; ++kt) {
    __syncthreads();
    #pragma unroll
    for (int p = 0; p < 4; ++p) As[ld_d * 36 + p * 8 + ld_r] = aP[p];
    #pragma unroll
    for (int p = 0; p < 8; ++p) Ws[(p * 4 + lw_k) * 68 + lw_n] = wP[p];
    __syncthreads();
    if (kt < 7) {
      const int k0 = (kt + 1) * 32;
      #pragma unroll
      for (int p = 0; p < 4; ++p) aP[p] = A[(size_t)(p * 8 + ld_r) * DD_ + k0 + ld_d];
      #pragma unroll
      for (int p = 0; p < 8; ++p) wP[p] = W[(size_t)(k0 + p * 4 + lw_k) * H_ + col0 + lw_n];
    }
    #pragma unroll
    for (int kk = 0; kk < 32; ++kk) {
      const float2 a = *(const float2*)&As[kk * 36 + tm * 2];
      const float4 w = *(const float4*)&Ws[kk * 68 + tn * 4];
      acc[0][0] = fmaf(a.x, w.x, acc[0][0]);
      acc[0][1] = fmaf(a.x, w.y, acc[0][1]);
      acc[0][2] = fmaf(a.x, w.z, acc[0][2]);
      acc[0][3] = fmaf(a.x, w.w, acc[0][3]);
      acc[1][0] = fmaf(a.y, w.x, acc[1][0]);
      acc[1][1] = fmaf(a.y, w.y, acc[1][1]);
      acc[1][2] = fmaf(a.y, w.z, acc[1][2]);
      acc[1][3] = fmaf(a.y, w.w, acc[1][3]);
    }
  }

  if (isQ) {
    #pragma unroll
    for (int i = 0; i < 2; ++i) {
      *(float4*)&qp[(size_t)(row0 + tm * 2 + i) * H_ + col0 + tn * 4] =
          make_float4(acc[i][0], acc[i][1], acc[i][2], acc[i][3]);
    }
  } else {
    #pragma unroll
    for (int i = 0; i < 2; ++i)
      #pragma unroll
      for (int j = 0; j < 4; ++j)
        Ts[(tn * 4 + j) * 36 + tm * 2 + i] = acc[i][j];
    __syncthreads();
    const int keyrow = row0 - 512;
    const int b = keyrow >> 10;
    const int kbase = keyrow & (NK_ - 1);
    const int hh = tid >> 2;
    const int kg = (tid & 3) * 8;
    float* dst = kpT + ((size_t)(b * H_ + col0 + hh)) * NK_ + kbase + kg;
    #pragma unroll
    for (int p = 0; p < 2; ++p)
      *(float4*)&dst[p * 4] = *(const float4*)&Ts[hh * 36 + kg + p * 4];
  }
}

// Fused scores + masked softmax + PV.  One block per 2 q rows; 1024 threads
// (16 waves) -> 4096 waves chip-wide = 50% occupancy cap (was 25%).
// Phase 1: h-group g = tid>>9 covers h in [128g,128g+128); thread owns k = 2t..2t+1
//   (float2, shared across BOTH q rows) with 4-deep register prefetch.
//   score = wsum - sum_h (2 v_h)*rcp(1+exp2((q_h+k_h)*2*log2e))  [tanh identity]
//   Threads with k >= valid_len skip the h-loop entirely.
// Phase 2: combine h-halves, masked softmax per q row (16-wave LDS reduce).
// Phase 3: wave w owns k in [64w,64w+64) ∩ [0,vl) for BOTH q rows (V read once);
//   lane owns d = 4*lane, 4-deep V prefetch; partials combined through LDS.
__global__ __launch_bounds__(1024) void fused_attn_kernel(
    const float* __restrict__ qp, const float* __restrict__ kpT,
    const float* __restrict__ v_w, const float* __restrict__ values,
    const int* __restrict__ valid_lens, float* __restrict__ out) {
  __shared__ float2 qs2[H_];            // {q0*C2, q1*C2}
  __shared__ float w2s[H_];
  __shared__ float reds[4];
  __shared__ float s_half[2][2][NK_];   // [h-half][qi][k] partials -> weights (32KB)
  __shared__ float redm[2][8];
  __shared__ float redsum[2][8];
  __shared__ float red[2][16][DV_];     // PV wave partials (32KB)

  const int tid = threadIdx.x;  // 0..1023
  // Batch<->XCD affinity: XCD pair {2b,2b+1} only touches batch b.
  const int n = blockIdx.x;     // 0..255
  const int xcd = n & 7;
  const int b = xcd >> 1;
  const int idx = ((n >> 3) << 1) | (xcd & 1);  // 0..63 q-pair within batch
  const int qrow = b * NQ_ + idx * 2;

  int vl = valid_lens[b];
  vl = vl < 1 ? 1 : (vl > NK_ ? NK_ : vl);

  const float C2 = 2.8853900817779268f;  // 2*log2(e)
  if (tid < H_) {
    const float vw = v_w[tid];
    w2s[tid] = 2.0f * vw;
    const float q0 = qp[(size_t)qrow * H_ + tid];
    const float q1 = qp[(size_t)(qrow + 1) * H_ + tid];
    qs2[tid] = make_float2(q0 * C2, q1 * C2);
    float s = wave_sum(vw);
    if ((tid & 63) == 0) reds[tid >> 6] = s;
  }
  __syncthreads();
  const float wsum = reds[0] + reds[1] + reds[2] + reds[3];

  // ---- Phase 1: partial score sums over this group's h-half ----
  const int g = tid >> 9;
  const int t = tid & 511;
  const int k0 = t * 2;
  if (k0 < vl) {
    float a00 = 0.f, a01 = 0.f, a10 = 0.f, a11 = 0.f;
    const float* kp = kpT + ((size_t)(b * H_ + g * 128)) * NK_ + k0;
    const float* w2p = w2s + g * 128;
    const float2* q2p = qs2 + g * 128;
    float2 c0 = *(const float2*)(kp + 0 * (size_t)NK_);
    float2 c1 = *(const float2*)(kp + 1 * (size_t)NK_);
    float2 c2 = *(const float2*)(kp + 2 * (size_t)NK_);
    float2 c3 = *(const float2*)(kp + 3 * (size_t)NK_);
#define CONSUME(kv, h)                                                     \
    {                                                                      \
      const float w2 = w2p[h];                                             \
      const float2 q2 = q2p[h];                                            \
      const float e00 = __builtin_amdgcn_exp2f(fmaf((kv).x, C2, q2.x));    \
      const float e01 = __builtin_amdgcn_exp2f(fmaf((kv).y, C2, q2.x));    \
      const float e10 = __builtin_amdgcn_exp2f(fmaf((kv).x, C2, q2.y));    \
      const float e11 = __builtin_amdgcn_exp2f(fmaf((kv).y, C2, q2.y));    \
      a00 = fmaf(w2, __builtin_amdgcn_rcpf(1.0f + e00), a00);              \
      a01 = fmaf(w2, __builtin_amdgcn_rcpf(1.0f + e01), a01);              \
      a10 = fmaf(w2, __builtin_amdgcn_rcpf(1.0f + e10), a10);              \
      a11 = fmaf(w2, __builtin_amdgcn_rcpf(1.0f + e11), a11);              \
    }
    for (int gg = 0; gg < 31; ++gg) {
      const int hb = gg * 4;
      const float2 n0 = *(const float2*)(kp + (size_t)(hb + 4) * NK_);
      const float2 n1 = *(const float2*)(kp + (size_t)(hb + 5) * NK_);
      const float2 n2 = *(const float2*)(kp + (size_t)(hb + 6) * NK_);
      const float2 n3 = *(const float2*)(kp + (size_t)(hb + 7) * NK_);
      CONSUME(c0, hb + 0)
      CONSUME(c1, hb + 1)
      CONSUME(c2, hb + 2)
      CONSUME(c3, hb + 3)
      c0 = n0; c1 = n1; c2 = n2; c3 = n3;
    }
    CONSUME(c0, 124)
    CONSUME(c1, 125)
    CONSUME(c2, 126)
    CONSUME(c3, 127)
#undef CONSUME
    *(float2*)&s_half[g][0][k0] = make_float2(a00, a01);
    *(float2*)&s_half[g][1][k0] = make_float2(a10, a11);
  }
  __syncthreads();

  // ---- Phase 2: combine halves + masked softmax per q row ----
  const int qi = tid >> 9;
  const int j2 = (tid & 511) * 2;
  const float2 pA = *(const float2*)&s_half[0][qi][j2];
  const float2 pB = *(const float2*)&s_half[1][qi][j2];
  const float s0 = wsum - (pA.x + pB.x);
  const float s1 = wsum - (pA.y + pB.y);
  const float NEG = -3.0e38f;
  float m = NEG;
  m = fmaxf(m, (j2 + 0 < vl) ? s0 : NEG);
  m = fmaxf(m, (j2 + 1 < vl) ? s1 : NEG);
  m = wave_max(m);
  if ((tid & 63) == 0) redm[qi][(tid >> 6) & 7] = m;
  __syncthreads();
  float M = redm[qi][0];
  #pragma unroll
  for (int r = 1; r < 8; ++r) M = fmaxf(M, redm[qi][r]);
  const float CE = 1.4426950408889634f;  // log2(e)
  const float p0 = (j2 + 0 < vl) ? __builtin_amdgcn_exp2f((s0 - M) * CE) : 0.0f;
  const float p1 = (j2 + 1 < vl) ? __builtin_amdgcn_exp2f((s1 - M) * CE) : 0.0f;
  float psum = wave_sum(p0 + p1);
  if ((tid & 63) == 0) redsum[qi][(tid >> 6) & 7] = psum;
  __syncthreads();
  float S = 0.f;
  #pragma unroll
  for (int r = 0; r < 8; ++r) S += redsum[qi][r];
  const float inv = 1.0f / S;
  *(float2*)&s_half[0][qi][j2] = make_float2(p0 * inv, p1 * inv);
  __syncthreads();

  // ---- Phase 3: PV with 4-deep V prefetch (V rows shared by both q rows) ----
  const int w = tid >> 6;
  const int lane = tid & 63;
  const int d0 = lane * 4;
  float4 pa0 = make_float4(0.f, 0.f, 0.f, 0.f);
  float4 pa1 = make_float4(0.f, 0.f, 0.f, 0.f);
  const int kbeg = w * (NK_ / 16);
  const int kend = (kbeg + NK_ / 16) < vl ? (kbeg + NK_ / 16) : vl;
  const float* vb = values + (size_t)b * NK_ * DV_ + d0;
#define PVSTEP(v4, kk)                                                     \
    {                                                                      \
      const float w0 = s_half[0][0][kk];                                   \
      const float w1 = s_half[0][1][kk];                                   \
      pa0.x = fmaf(w0, (v4).x, pa0.x);                                     \
      pa0.y = fmaf(w0, (v4).y, pa0.y);                                     \
      pa0.z = fmaf(w0, (v4).z, pa0.z);                                     \
      pa0.w = fmaf(w0, (v4).w, pa0.w);                                     \
      pa1.x = fmaf(w1, (v4).x, pa1.x);                                     \
      pa1.y = fmaf(w1, (v4).y, pa1.y);                                     \
      pa1.z = fmaf(w1, (v4).z, pa1.z);                                     \
      pa1.w = fmaf(w1, (v4).w, pa1.w);                                     \
    }
  int k = kbeg;
  if (k + 4 <= kend) {
    float4 v0 = *(const float4*)(vb + (size_t)(k + 0) * DV_);
    float4 v1 = *(const float4*)(vb + (size_t)(k + 1) * DV_);
    float4 v2 = *(const float4*)(vb + (size_t)(k + 2) * DV_);
    float4 v3 = *(const float4*)(vb + (size_t)(k + 3) * DV_);
    for (; k + 8 <= kend; k += 4) {
      const float4 u0 = *(const float4*)(vb + (size_t)(k + 4) * DV_);
      const float4 u1 = *(const float4*)(vb + (size_t)(k + 5) * DV_);
      const float4 u2 = *(const float4*)(vb + (size_t)(k + 6) * DV_);
      const float4 u3 = *(const float4*)(vb + (size_t)(k + 7) * DV_);
      PVSTEP(v0, k + 0)
      PVSTEP(v1, k + 1)
      PVSTEP(v2, k + 2)
      PVSTEP(v3, k + 3)
      v0 = u0; v1 = u1; v2 = u2; v3 = u3;
    }
    PVSTEP(v0, k + 0)
    PVSTEP(v1, k + 1)
    PVSTEP(v2, k + 2)
    PVSTEP(v3, k + 3)
    k += 4;
  }
  for (; k < kend; ++k) {
    const float4 v4 = *(const float4*)(vb + (size_t)k * DV_);
    PVSTEP(v4, k)
  }
#undef PVSTEP
  *(float4*)&red[0][w][d0] = pa0;
  *(float4*)&red[1][w][d0] = pa1;
  __syncthreads();

  // Combine 16 wave-partials per q row; coalesced store.
  if (tid < 512) {
    const int oqi = tid >> 8;
    const int d = tid & 255;
    float s = 0.f;
    #pragma unroll
    for (int ww = 0; ww < 16; ++ww) s += red[oqi][ww][d];
    out[(size_t)(qrow + oqi) * DV_ + d] = s;
  }
}

extern "C" void kernel_launch(void* const* d_in, const int* in_sizes, int n_in,
                              void* d_out, int out_size, void* d_ws, size_t ws_size,
                              hipStream_t stream) {
  const float* queries = (const float*)d_in[0];  // (B, NQ, DQ)
  const float* keys    = (const float*)d_in[1];  // (B, NK, DK)
  const float* values  = (const float*)d_in[2];  // (B, NK, DV)
  const int*   vlens   = (const int*)d_in[3];    // (B,)
  const float* W_q     = (const float*)d_in[4];  // (DQ, H)
  const float* W_k     = (const float*)d_in[5];  // (DK, H)
  const float* v_w     = (const float*)d_in[6];  // (H,)
  float* out = (float*)d_out;                    // (B, NQ, DV)

  // Workspace layout (floats): qp | kpT  = 0.5MB + 4MB
  float* qp  = (float*)d_ws;                  // [B*NQ][H]
  float* kpT = qp + (size_t)B_ * NQ_ * H_;    // [B][H][NK]

  proj_merged_kernel<<<dim3((512 + B_ * NK_) / 32, H_ / 64), 256, 0, stream>>>(
      queries, keys, W_q, W_k, qp, kpT);
  fused_attn_kernel<<<B_ * NQ_ / 2, 1024, 0, stream>>>(qp, kpT, v_w, values, vlens, out);
}

// Round 16
// 120.151 us; speedup vs baseline: 1.0918x; 1.0144x over previous
//
#include <hip/hip_runtime.h>

// Sizes fixed by the reference problem.
#define B_   4
#define NQ_  128
#define NK_  1024
#define DD_  256   // DQ == DK
#define H_   256
#define DV_  256

__device__ __forceinline__ float wave_sum(float v) {
  #pragma unroll
  for (int o = 32; o; o >>= 1) v += __shfl_xor(v, o);
  return v;
}
__device__ __forceinline__ float wave_max(float v) {
  #pragma unroll
  for (int o = 32; o; o >>= 1) v = fmaxf(v, __shfl_xor(v, o));
  return v;
}

// Merged projection GEMM over 4608 rows (32-row x 64-col tiles, 576 blocks, BK=32):
//   rows [0,512):    qp[row][h]   = queries * W_q   (row-major store)
//   rows [512,4608): kpT[b][h][k] = keys * W_k      (transposed store via LDS)
__global__ __launch_bounds__(256) void proj_merged_kernel(
    const float* __restrict__ queries, const float* __restrict__ keys,
    const float* __restrict__ W_q, const float* __restrict__ W_k,
    float* __restrict__ qp, float* __restrict__ kpT) {
  __shared__ float As[32 * 36];   // [k32][row32] (+pad)
  __shared__ float Ws[32 * 68];   // [k32][col64] (+pad)
  __shared__ float Ts[64 * 36];   // transpose staging [h64][k32] (+pad)
  const int tid  = threadIdx.x;
  const int row0 = blockIdx.x * 32;
  const int col0 = blockIdx.y * 64;
  const bool isQ = row0 < 512;
  const float* A = isQ ? queries + (size_t)row0 * DD_
                       : keys + (size_t)(row0 - 512) * DD_;
  const float* W = isQ ? W_q : W_k;
  const int ld_d = tid & 31, ld_r = tid >> 5;   // A loader: 32 k x 8 r (x4 passes)
  const int lw_n = tid & 63, lw_k = tid >> 6;   // W loader: 64 n x 4 k (x8 passes)
  const int tn = tid & 15, tm = tid >> 4;       // compute: 16 cols x 16 rows

  float aP[4], wP[8];
  #pragma unroll
  for (int p = 0; p < 4; ++p) aP[p] = A[(size_t)(p * 8 + ld_r) * DD_ + ld_d];
  #pragma unroll
  for (int p = 0; p < 8; ++p) wP[p] = W[(size_t)(p * 4 + lw_k) * H_ + col0 + lw_n];

  float acc[2][4] = {};
  for (int kt = 0; kt < 8; ++kt) {
    __syncthreads();
    #pragma unroll
    for (int p = 0; p < 4; ++p) As[ld_d * 36 + p * 8 + ld_r] = aP[p];
    #pragma unroll
    for (int p = 0; p < 8; ++p) Ws[(p * 4 + lw_k) * 68 + lw_n] = wP[p];
    __syncthreads();
    if (kt < 7) {
      const int k0 = (kt + 1) * 32;
      #pragma unroll
      for (int p = 0; p < 4; ++p) aP[p] = A[(size_t)(p * 8 + ld_r) * DD_ + k0 + ld_d];
      #pragma unroll
      for (int p = 0; p < 8; ++p) wP[p] = W[(size_t)(k0 + p * 4 + lw_k) * H_ + col0 + lw_n];
    }
    #pragma unroll
    for (int kk = 0; kk < 32; ++kk) {
      const float2 a = *(const float2*)&As[kk * 36 + tm * 2];
      const float4 w = *(const float4*)&Ws[kk * 68 + tn * 4];
      acc[0][0] = fmaf(a.x, w.x, acc[0][0]);
      acc[0][1] = fmaf(a.x, w.y, acc[0][1]);
      acc[0][2] = fmaf(a.x, w.z, acc[0][2]);
      acc[0][3] = fmaf(a.x, w.w, acc[0][3]);
      acc[1][0] = fmaf(a.y, w.x, acc[1][0]);
      acc[1][1] = fmaf(a.y, w.y, acc[1][1]);
      acc[1][2] = fmaf(a.y, w.z, acc[1][2]);
      acc[1][3] = fmaf(a.y, w.w, acc[1][3]);
    }
  }

  if (isQ) {
    #pragma unroll
    for (int i = 0; i < 2; ++i) {
      *(float4*)&qp[(size_t)(row0 + tm * 2 + i) * H_ + col0 + tn * 4] =
          make_float4(acc[i][0], acc[i][1], acc[i][2], acc[i][3]);
    }
  } else {
    #pragma unroll
    for (int i = 0; i < 2; ++i)
      #pragma unroll
      for (int j = 0; j < 4; ++j)
        Ts[(tn * 4 + j) * 36 + tm * 2 + i] = acc[i][j];
    __syncthreads();
    const int keyrow = row0 - 512;
    const int b = keyrow >> 10;
    const int kbase = keyrow & (NK_ - 1);
    const int hh = tid >> 2;
    const int kg = (tid & 3) * 8;
    float* dst = kpT + ((size_t)(b * H_ + col0 + hh)) * NK_ + kbase + kg;
    #pragma unroll
    for (int p = 0; p < 2; ++p)
      *(float4*)&dst[p * 4] = *(const float4*)&Ts[hh * 36 + kg + p * 4];
  }
}

// Fused scores + masked softmax + PV.  One block per 2 q rows; 1024 threads.
// Phase 1: 4 h-quarter groups g = tid>>8 (h in [64g, 64g+64)); thread owns
//   k = 4(tid&255)..+3 (float4) for BOTH q rows, with 8-deep (two-batch-of-4)
//   rolling register prefetch: ~384 issue-cycles in flight >= ~300cy L2 latency.
//   score = wsum - sum_h (2 v_h)*rcp(1+exp2((q_h+k_h)*2*log2e))  [tanh identity]
//   Threads with k >= valid_len skip the h-loop entirely.
// Phase 2: combine 4 quarters, masked softmax per q row (8 waves per q row).
// Phase 3: wave w owns k in [64w,64w+64) ∩ [0,vl) for BOTH q rows; lane owns
//   d = 4*lane, 4-deep V prefetch; 16 wave-partials combined through LDS.
__global__ __launch_bounds__(1024) void fused_attn_kernel(
    const float* __restrict__ qp, const float* __restrict__ kpT,
    const float* __restrict__ v_w, const float* __restrict__ values,
    const int* __restrict__ valid_lens, float* __restrict__ out) {
  __shared__ float2 qs2[H_];            // {q0*C2, q1*C2}
  __shared__ float w2s[H_];
  __shared__ float reds[4];
  __shared__ float s_q[4][2][NK_];      // [h-quarter][qi][k] partials (32KB)
  __shared__ float redm[2][8];
  __shared__ float redsum[2][8];
  __shared__ float red[2][16][DV_];     // PV wave partials (32KB)

  const int tid = threadIdx.x;  // 0..1023
  // Batch<->XCD affinity: XCD pair {2b,2b+1} only touches batch b.
  const int n = blockIdx.x;     // 0..255
  const int xcd = n & 7;
  const int b = xcd >> 1;
  const int idx = ((n >> 3) << 1) | (xcd & 1);  // 0..63 q-pair within batch
  const int qrow = b * NQ_ + idx * 2;

  int vl = valid_lens[b];
  vl = vl < 1 ? 1 : (vl > NK_ ? NK_ : vl);

  const float C2 = 2.8853900817779268f;  // 2*log2(e)
  if (tid < H_) {
    const float vw = v_w[tid];
    w2s[tid] = 2.0f * vw;
    const float q0 = qp[(size_t)qrow * H_ + tid];
    const float q1 = qp[(size_t)(qrow + 1) * H_ + tid];
    qs2[tid] = make_float2(q0 * C2, q1 * C2);
    float s = wave_sum(vw);
    if ((tid & 63) == 0) reds[tid >> 6] = s;
  }
  __syncthreads();
  const float wsum = reds[0] + reds[1] + reds[2] + reds[3];

  // ---- Phase 1: partial score sums over this group's h-quarter (64 rows) ----
  const int g = tid >> 8;       // 0..3
  const int t = tid & 255;
  const int k0 = t * 4;
  if (k0 < vl) {
    float a0x = 0.f, a0y = 0.f, a0z = 0.f, a0w = 0.f;
    float a1x = 0.f, a1y = 0.f, a1z = 0.f, a1w = 0.f;
    const float* kp = kpT + ((size_t)(b * H_ + g * 64)) * NK_ + k0;
    const float* w2p = w2s + g * 64;
    const float2* q2p = qs2 + g * 64;
    float4 c0 = *(const float4*)(kp + 0 * (size_t)NK_);
    float4 c1 = *(const float4*)(kp + 1 * (size_t)NK_);
    float4 c2 = *(const float4*)(kp + 2 * (size_t)NK_);
    float4 c3 = *(const float4*)(kp + 3 * (size_t)NK_);
    float4 e0 = *(const float4*)(kp + 4 * (size_t)NK_);
    float4 e1 = *(const float4*)(kp + 5 * (size_t)NK_);
    float4 e2 = *(const float4*)(kp + 6 * (size_t)NK_);
    float4 e3 = *(const float4*)(kp + 7 * (size_t)NK_);
#define CONSUME(kv, h)                                                     \
    {                                                                      \
      const float w2 = w2p[h];                                             \
      const float2 q2 = q2p[h];                                            \
      const float e0x_ = __builtin_amdgcn_exp2f(fmaf((kv).x, C2, q2.x));   \
      const float e0y_ = __builtin_amdgcn_exp2f(fmaf((kv).y, C2, q2.x));   \
      const float e0z_ = __builtin_amdgcn_exp2f(fmaf((kv).z, C2, q2.x));   \
      const float e0w_ = __builtin_amdgcn_exp2f(fmaf((kv).w, C2, q2.x));   \
      const float e1x_ = __builtin_amdgcn_exp2f(fmaf((kv).x, C2, q2.y));   \
      const float e1y_ = __builtin_amdgcn_exp2f(fmaf((kv).y, C2, q2.y));   \
      const float e1z_ = __builtin_amdgcn_exp2f(fmaf((kv).z, C2, q2.y));   \
      const float e1w_ = __builtin_amdgcn_exp2f(fmaf((kv).w, C2, q2.y));   \
      a0x = fmaf(w2, __builtin_amdgcn_rcpf(1.0f + e0x_), a0x);             \
      a0y = fmaf(w2, __builtin_amdgcn_rcpf(1.0f + e0y_), a0y);             \
      a0z = fmaf(w2, __builtin_amdgcn_rcpf(1.0f + e0z_), a0z);             \
      a0w = fmaf(w2, __builtin_amdgcn_rcpf(1.0f + e0w_), a0w);             \
      a1x = fmaf(w2, __builtin_amdgcn_rcpf(1.0f + e1x_), a1x);             \
      a1y = fmaf(w2, __builtin_amdgcn_rcpf(1.0f + e1y_), a1y);             \
      a1z = fmaf(w2, __builtin_amdgcn_rcpf(1.0f + e1z_), a1z);             \
      a1w = fmaf(w2, __builtin_amdgcn_rcpf(1.0f + e1w_), a1w);             \
    }
    // 16 batches of 4 rows; consume batch i while batches i+1, i+2 in flight.
    for (int i = 0; i < 14; ++i) {
      const int hb = i * 4;
      const float4 n0 = *(const float4*)(kp + (size_t)(hb + 8) * NK_);
      const float4 n1 = *(const float4*)(kp + (size_t)(hb + 9) * NK_);
      const float4 n2 = *(const float4*)(kp + (size_t)(hb + 10) * NK_);
      const float4 n3 = *(const float4*)(kp + (size_t)(hb + 11) * NK_);
      CONSUME(c0, hb + 0)
      CONSUME(c1, hb + 1)
      CONSUME(c2, hb + 2)
      CONSUME(c3, hb + 3)
      c0 = e0; c1 = e1; c2 = e2; c3 = e3;
      e0 = n0; e1 = n1; e2 = n2; e3 = n3;
    }
    CONSUME(c0, 56)
    CONSUME(c1, 57)
    CONSUME(c2, 58)
    CONSUME(c3, 59)
    CONSUME(e0, 60)
    CONSUME(e1, 61)
    CONSUME(e2, 62)
    CONSUME(e3, 63)
#undef CONSUME
    *(float4*)&s_q[g][0][k0] = make_float4(a0x, a0y, a0z, a0w);
    *(float4*)&s_q[g][1][k0] = make_float4(a1x, a1y, a1z, a1w);
  }
  __syncthreads();

  // ---- Phase 2: combine quarters + masked softmax per q row ----
  const int qi = tid >> 9;              // 0..1
  const int j2 = (tid & 511) * 2;       // 2 k per thread
  const float2 pA = *(const float2*)&s_q[0][qi][j2];
  const float2 pB = *(const float2*)&s_q[1][qi][j2];
  const float2 pC = *(const float2*)&s_q[2][qi][j2];
  const float2 pD = *(const float2*)&s_q[3][qi][j2];
  const float s0 = wsum - (pA.x + pB.x + pC.x + pD.x);
  const float s1 = wsum - (pA.y + pB.y + pC.y + pD.y);
  const float NEG = -3.0e38f;
  float m = NEG;
  m = fmaxf(m, (j2 + 0 < vl) ? s0 : NEG);
  m = fmaxf(m, (j2 + 1 < vl) ? s1 : NEG);
  m = wave_max(m);
  if ((tid & 63) == 0) redm[qi][(tid >> 6) & 7] = m;
  __syncthreads();
  float M = redm[qi][0];
  #pragma unroll
  for (int r = 1; r < 8; ++r) M = fmaxf(M, redm[qi][r]);
  const float CE = 1.4426950408889634f;  // log2(e)
  const float p0 = (j2 + 0 < vl) ? __builtin_amdgcn_exp2f((s0 - M) * CE) : 0.0f;
  const float p1 = (j2 + 1 < vl) ? __builtin_amdgcn_exp2f((s1 - M) * CE) : 0.0f;
  float psum = wave_sum(p0 + p1);
  if ((tid & 63) == 0) redsum[qi][(tid >> 6) & 7] = psum;
  __syncthreads();
  float S = 0.f;
  #pragma unroll
  for (int r = 0; r < 8; ++r) S += redsum[qi][r];
  const float inv = 1.0f / S;
  *(float2*)&s_q[0][qi][j2] = make_float2(p0 * inv, p1 * inv);
  __syncthreads();

  // ---- Phase 3: PV with 4-deep V prefetch (V rows shared by both q rows) ----
  const int w = tid >> 6;
  const int lane = tid & 63;
  const int d0 = lane * 4;
  float4 pa0 = make_float4(0.f, 0.f, 0.f, 0.f);
  float4 pa1 = make_float4(0.f, 0.f, 0.f, 0.f);
  const int kbeg = w * (NK_ / 16);
  const int kend = (kbeg + NK_ / 16) < vl ? (kbeg + NK_ / 16) : vl;
  const float* vb = values + (size_t)b * NK_ * DV_ + d0;
#define PVSTEP(v4, kk)                                                     \
    {                                                                      \
      const float w0 = s_q[0][0][kk];                                      \
      const float w1 = s_q[0][1][kk];                                      \
      pa0.x = fmaf(w0, (v4).x, pa0.x);                                     \
      pa0.y = fmaf(w0, (v4).y, pa0.y);                                     \
      pa0.z = fmaf(w0, (v4).z, pa0.z);                                     \
      pa0.w = fmaf(w0, (v4).w, pa0.w);                                     \
      pa1.x = fmaf(w1, (v4).x, pa1.x);                                     \
      pa1.y = fmaf(w1, (v4).y, pa1.y);                                     \
      pa1.z = fmaf(w1, (v4).z, pa1.z);                                     \
      pa1.w = fmaf(w1, (v4).w, pa1.w);                                     \
    }
  int k = kbeg;
  if (k + 4 <= kend) {
    float4 v0 = *(const float4*)(vb + (size_t)(k + 0) * DV_);
    float4 v1 = *(const float4*)(vb + (size_t)(k + 1) * DV_);
    float4 v2 = *(const float4*)(vb + (size_t)(k + 2) * DV_);
    float4 v3 = *(const float4*)(vb + (size_t)(k + 3) * DV_);
    for (; k + 8 <= kend; k += 4) {
      const float4 u0 = *(const float4*)(vb + (size_t)(k + 4) * DV_);
      const float4 u1 = *(const float4*)(vb + (size_t)(k + 5) * DV_);
      const float4 u2 = *(const float4*)(vb + (size_t)(k + 6) * DV_);
      const float4 u3 = *(const float4*)(vb + (size_t)(k + 7) * DV_);
      PVSTEP(v0, k + 0)
      PVSTEP(v1, k + 1)
      PVSTEP(v2, k + 2)
      PVSTEP(v3, k + 3)
      v0 = u0; v1 = u1; v2 = u2; v3 = u3;
    }
    PVSTEP(v0, k + 0)
    PVSTEP(v1, k + 1)
    PVSTEP(v2, k + 2)
    PVSTEP(v3, k + 3)
    k += 4;
  }
  for (; k < kend; ++k) {
    const float4 v4 = *(const float4*)(vb + (size_t)k * DV_);
    PVSTEP(v4, k)
  }
#undef PVSTEP
  *(float4*)&red[0][w][d0] = pa0;
  *(float4*)&red[1][w][d0] = pa1;
  __syncthreads();

  // Combine 16 wave-partials per q row; coalesced store.
  if (tid < 512) {
    const int oqi = tid >> 8;
    const int d = tid & 255;
    float s = 0.f;
    #pragma unroll
    for (int ww = 0; ww < 16; ++ww) s += red[oqi][ww][d];
    out[(size_t)(qrow + oqi) * DV_ + d] = s;
  }
}

extern "C" void kernel_launch(void* const* d_in, const int* in_sizes, int n_in,
                              void* d_out, int out_size, void* d_ws, size_t ws_size,
                              hipStream_t stream) {
  const float* queries = (const float*)d_in[0];  // (B, NQ, DQ)
  const float* keys    = (const float*)d_in[1];  // (B, NK, DK)
  const float* values  = (const float*)d_in[2];  // (B, NK, DV)
  const int*   vlens   = (const int*)d_in[3];    // (B,)
  const float* W_q     = (const float*)d_in[4];  // (DQ, H)
  const float* W_k     = (const float*)d_in[5];  // (DK, H)
  const float* v_w     = (const float*)d_in[6];  // (H,)
  float* out = (float*)d_out;                    // (B, NQ, DV)

  // Workspace layout (floats): qp | kpT  = 0.5MB + 4MB
  float* qp  = (float*)d_ws;                  // [B*NQ][H]
  float* kpT = qp + (size_t)B_ * NQ_ * H_;    // [B][H][NK]

  proj_merged_kernel<<<dim3((512 + B_ * NK_) / 32, H_ / 64), 256, 0, stream>>>(
      queries, keys, W_q, W_k, qp, kpT);
  fused_attn_kernel<<<B_ * NQ_ / 2, 1024, 0, stream>>>(qp, kpT, v_w, values, vlens, out);
}